// Round 3
// baseline (1517.713 us; speedup 1.0000x reference)
//
#include <hip/hip_runtime.h>
#include <hip/hip_bf16.h>
#include <math.h>

#define NB 4
#define LL 16384
#define CC 256
#define NHD 8
#define DH 32
#define MROWS (NB*LL)   // 65536

typedef __hip_bfloat16 bf16;

__device__ __forceinline__ float u2f(unsigned short u) {
  return __uint_as_float(((unsigned)u) << 16);
}
__device__ __forceinline__ unsigned short f2u(float f) {
  bf16 t = __float2bfloat16(f);
  unsigned short u;
  __builtin_memcpy(&u, &t, 2);
  return u;
}

// ---------------- GEMM: C[M,N] = act( A[M,K] @ B[N,K]^T ) ----------------
// A row m: k < K0 -> A0 (f32 input, ld=K0); k >= K0 -> A1 (bf16 ws, ld=K-K0)
// B: f32 weights. C: bf16 workspace.
template<bool RELU>
__global__ __launch_bounds__(256) void gemm_f32in(
    const float* __restrict__ A0, int K0, const bf16* __restrict__ A1,
    const float* __restrict__ B, bf16* __restrict__ C,
    int M, int N, int K)
{
  __shared__ __align__(16) float As[16][64];
  __shared__ __align__(16) float Bs[16][64];
  const int tid = threadIdx.x;
  const int tx = tid & 15, ty = tid >> 4;
  const int bm = blockIdx.y, bn = blockIdx.x;
  const int lr = tid >> 2, lk4 = (tid & 3) << 2;
  float acc[4][4] = {};
  for (int kt = 0; kt < K; kt += 16) {
    int gk = kt + lk4;
    { // A tile (64 rows x 16 k), stored k-major
      int gr = bm*64 + lr;
      float t0,t1,t2,t3;
      if (gk < K0) {
        float4 f = *(const float4*)(A0 + (size_t)gr*K0 + gk);
        t0=f.x; t1=f.y; t2=f.z; t3=f.w;
      } else {
        ushort4 u = *(const ushort4*)(A1 + (size_t)gr*(size_t)(K-K0) + (gk-K0));
        t0=u2f(u.x); t1=u2f(u.y); t2=u2f(u.z); t3=u2f(u.w);
      }
      As[lk4+0][lr] = t0;
      As[lk4+1][lr] = t1;
      As[lk4+2][lr] = t2;
      As[lk4+3][lr] = t3;
    }
    { // B tile (64 cols x 16 k)
      int gc = bn*64 + lr;
      float4 f = *(const float4*)(B + (size_t)gc*K + gk);
      Bs[lk4+0][lr] = f.x;
      Bs[lk4+1][lr] = f.y;
      Bs[lk4+2][lr] = f.z;
      Bs[lk4+3][lr] = f.w;
    }
    __syncthreads();
    #pragma unroll
    for (int kk=0; kk<16; kk++) {
      float4 a4 = *(const float4*)&As[kk][ty<<2];
      float4 b4 = *(const float4*)&Bs[kk][tx<<2];
      float av[4] = {a4.x,a4.y,a4.z,a4.w};
      float bv[4] = {b4.x,b4.y,b4.z,b4.w};
      #pragma unroll
      for (int i=0;i<4;i++)
        #pragma unroll
        for (int j=0;j<4;j++)
          acc[i][j] = fmaf(av[i], bv[j], acc[i][j]);
    }
    __syncthreads();
  }
  int row0 = bm*64 + (ty<<2);
  int col0 = bn*64 + (tx<<2);
  #pragma unroll
  for (int i=0;i<4;i++) {
    float o[4] = {acc[i][0], acc[i][1], acc[i][2], acc[i][3]};
    if (RELU) {
      #pragma unroll
      for (int j=0;j<4;j++) o[j] = fmaxf(o[j], 0.f);
    }
    ushort4 u;
    u.x = f2u(o[0]); u.y = f2u(o[1]); u.z = f2u(o[2]); u.w = f2u(o[3]);
    *(ushort4*)&C[(size_t)(row0+i)*N + col0] = u;
  }
}

// ---------------- elu+1 then interleaved RoPE, in-place on q and k --------
__global__ __launch_bounds__(256) void rope_elu_kernel(bf16* __restrict__ q, bf16* __restrict__ k)
{
  int idx = blockIdx.x*256 + threadIdx.x;   // one (row, pair); 128 pairs/row
  int row = idx >> 7;
  int p   = idx & 127;          // global pair in row
  int pp  = p & 15;             // pair in head
  int t   = pp >> 1;            // frequency index 0..7
  int l   = row & (LL-1);
  int gi  = l >> 7;             // grid row (W=128)
  int gj  = l & 127;            // grid col
  float pos = (pp & 1) ? (float)(gj+1) : (float)(gi+1);
  float dv  = expf(-1.15129254650564f * (float)t);  // ln(10000)/8
  float ang = pos * dv;
  float s = sinf(ang), c = cosf(ang);
  size_t base = ((size_t)row << 8) + (p << 1);
  ushort2 uq = *(const ushort2*)(q + base);
  float x0 = u2f(uq.x), x1 = u2f(uq.y);
  x0 = x0 > 0.f ? x0 + 1.f : expf(x0);
  x1 = x1 > 0.f ? x1 + 1.f : expf(x1);
  ushort2 oq; oq.x = f2u(fmaf(x0, c, -x1*s)); oq.y = f2u(fmaf(x1, c, x0*s));
  *(ushort2*)(q + base) = oq;
  ushort2 uk = *(const ushort2*)(k + base);
  float y0 = u2f(uk.x), y1 = u2f(uk.y);
  y0 = y0 > 0.f ? y0 + 1.f : expf(y0);
  y1 = y1 > 0.f ? y1 + 1.f : expf(y1);
  ushort2 ok; ok.x = f2u(fmaf(y0, c, -y1*s)); ok.y = f2u(fmaf(y1, c, y0*s));
  *(ushort2*)(k + base) = ok;
}

__global__ __launch_bounds__(256) void zero_kernel(float* __restrict__ p, int n)
{
  int i = blockIdx.x*256 + threadIdx.x;
  if (i < n) p[i] = 0.f;
}

// ---------------- KV[n,h,d,e] = sum_s K[n,s,h,d]*V[n,s,h,e]; Ksum too -----
__global__ __launch_bounds__(256) void kv_kernel(
    const bf16* __restrict__ Kr, const bf16* __restrict__ V,
    float* __restrict__ KV, float* __restrict__ Ksum)
{
  __shared__ __align__(16) float Ks[64][32];
  __shared__ __align__(16) float Vs[64][32];
  const int nh = blockIdx.x;               // n*8+h
  const int n = nh >> 3, h = nh & 7;
  const int s0 = blockIdx.y * 1024;        // 16 chunks of 1024
  const int tid = threadIdx.x;
  const int d = tid >> 3, e0 = (tid & 7) << 2;
  float acc[4] = {0.f,0.f,0.f,0.f};
  float ksl = 0.f;
  for (int sub = 0; sub < 1024; sub += 64) {
    #pragma unroll
    for (int i = 0; i < 4; i++) {
      int flat = (tid + i*256) << 1;        // pair index *2 = element
      int sl = flat >> 5, dd = flat & 31;
      size_t g = (((size_t)(n*LL + s0 + sub + sl) * NHD + h) << 5) + dd;
      ushort2 uk = *(const ushort2*)(Kr + g);
      ushort2 uv = *(const ushort2*)(V + g);
      Ks[sl][dd]   = u2f(uk.x); Ks[sl][dd+1] = u2f(uk.y);
      Vs[sl][dd]   = u2f(uv.x); Vs[sl][dd+1] = u2f(uv.y);
    }
    __syncthreads();
    #pragma unroll 8
    for (int ss = 0; ss < 64; ss++) {
      float kd = Ks[ss][d];
      float4 v4 = *(const float4*)&Vs[ss][e0];
      acc[0] = fmaf(kd, v4.x, acc[0]);
      acc[1] = fmaf(kd, v4.y, acc[1]);
      acc[2] = fmaf(kd, v4.z, acc[2]);
      acc[3] = fmaf(kd, v4.w, acc[3]);
    }
    if (tid < 32) {
      #pragma unroll 8
      for (int ss = 0; ss < 64; ss++) ksl += Ks[ss][tid];
    }
    __syncthreads();
  }
  float* kvp = KV + ((size_t)nh << 10) + (d << 5) + e0;
  atomicAdd(kvp+0, acc[0]); atomicAdd(kvp+1, acc[1]);
  atomicAdd(kvp+2, acc[2]); atomicAdd(kvp+3, acc[3]);
  if (tid < 32) atomicAdd(Ksum + (nh << 5) + tid, ksl);
}

// ---------------- out[l,h,e] = (Q_h . KV_h[:,e]) / (Q_h . Ksum_h + eps) ---
__global__ __launch_bounds__(256) void attn_out_kernel(
    const bf16* __restrict__ Qr, const float* __restrict__ KV,
    const float* __restrict__ Ksum, bf16* __restrict__ Out)
{
  __shared__ float KVs[8192];
  __shared__ float Kss[256];
  __shared__ float Qs[16][256];
  const int blk = blockIdx.x;            // 4096 blocks, 16 rows each
  const int n = blk >> 10;               // 1024 blocks per batch
  const int tid = threadIdx.x;
  const size_t rowBase = (size_t)blk * 16;
  for (int i = tid; i < 8192; i += 256) KVs[i] = KV[((size_t)n << 13) + i];
  Kss[tid] = Ksum[(n << 8) + tid];
  for (int i = tid; i < 4096; i += 256) ((float*)Qs)[i] = u2f(*(const unsigned short*)(Qr + (rowBase << 8) + i));
  __syncthreads();
  const int h = tid >> 5, e = tid & 31;
  const float* kvh = &KVs[(h << 10) + e];
  const float* ksh = &Kss[h << 5];
  for (int r = 0; r < 16; r++) {
    const float* qh = &Qs[r][h << 5];
    float denom = 1e-6f;
    float num = 0.f;
    #pragma unroll
    for (int d = 0; d < 32; d++) {
      float qd = qh[d];
      denom = fmaf(qd, ksh[d], denom);
      num   = fmaf(qd, kvh[d << 5], num);
    }
    Out[((rowBase + r) << 8) + tid] = __float2bfloat16(num / denom);
  }
}

// ---------------- LayerNorm over 256, bf16 ws in/out, f32 params ---------
__global__ __launch_bounds__(256) void ln_kernel(
    const bf16* __restrict__ X, const float* __restrict__ g, const float* __restrict__ b,
    bf16* __restrict__ Out)
{
  __shared__ float ps[4], psq[4], stat[2];
  int row = blockIdx.x, tid = threadIdx.x;
  float v = __bfloat162float(X[((size_t)row << 8) + tid]);
  float s = v, sq = v*v;
  #pragma unroll
  for (int o = 32; o > 0; o >>= 1) {
    s  += __shfl_down(s, o, 64);
    sq += __shfl_down(sq, o, 64);
  }
  if ((tid & 63) == 0) { ps[tid>>6] = s; psq[tid>>6] = sq; }
  __syncthreads();
  if (tid == 0) {
    float S = ps[0]+ps[1]+ps[2]+ps[3];
    float SQ = psq[0]+psq[1]+psq[2]+psq[3];
    float mean = S * (1.f/256.f);
    float var = SQ * (1.f/256.f) - mean*mean;
    stat[0] = mean; stat[1] = rsqrtf(var + 1e-5f);
  }
  __syncthreads();
  float mean = stat[0], rstd = stat[1];
  Out[((size_t)row << 8) + tid] = __float2bfloat16(
      (v - mean)*rstd*g[tid] + b[tid]);
}

// ---------------- final: out = x + LN(h2), f32 in x/out ------------------
__global__ __launch_bounds__(256) void ln_add_kernel(
    const bf16* __restrict__ X, const float* __restrict__ g, const float* __restrict__ b,
    const float* __restrict__ xin, float* __restrict__ Out)
{
  __shared__ float ps[4], psq[4], stat[2];
  int row = blockIdx.x, tid = threadIdx.x;
  size_t idx = ((size_t)row << 8) + tid;
  float v = __bfloat162float(X[idx]);
  float s = v, sq = v*v;
  #pragma unroll
  for (int o = 32; o > 0; o >>= 1) {
    s  += __shfl_down(s, o, 64);
    sq += __shfl_down(sq, o, 64);
  }
  if ((tid & 63) == 0) { ps[tid>>6] = s; psq[tid>>6] = sq; }
  __syncthreads();
  if (tid == 0) {
    float S = ps[0]+ps[1]+ps[2]+ps[3];
    float SQ = psq[0]+psq[1]+psq[2]+psq[3];
    float mean = S * (1.f/256.f);
    float var = SQ * (1.f/256.f) - mean*mean;
    stat[0] = mean; stat[1] = rsqrtf(var + 1e-5f);
  }
  __syncthreads();
  float mean = stat[0], rstd = stat[1];
  float lnv = (v - mean)*rstd*g[tid] + b[tid];
  Out[idx] = xin[idx] + lnv;
}

extern "C" void kernel_launch(void* const* d_in, const int* in_sizes, int n_in,
                              void* d_out, int out_size, void* d_ws, size_t ws_size,
                              hipStream_t stream) {
  const float* x   = (const float*)d_in[0];
  const float* src = (const float*)d_in[1];
  const float* Wq  = (const float*)d_in[2];
  const float* Wk  = (const float*)d_in[3];
  const float* Wv  = (const float*)d_in[4];
  const float* Wm  = (const float*)d_in[5];
  const float* W1  = (const float*)d_in[6];
  const float* W2  = (const float*)d_in[7];
  const float* g1  = (const float*)d_in[8];
  const float* b1  = (const float*)d_in[9];
  const float* g2  = (const float*)d_in[10];
  const float* b2  = (const float*)d_in[11];
  float* out = (float*)d_out;

  bf16* ws = (bf16*)d_ws;
  const size_t BUFH = (size_t)MROWS * CC;   // 16,777,216 bf16 = 32 MB
  bf16* B0 = ws;               // q -> msg -> h2
  bf16* B1 = ws + BUFH;        // k -> h1 (spans B1+B2)
  bf16* B2 = ws + 2*BUFH;      // v -> attn
  float* KV   = (float*)(ws + 3*BUFH);      // 32768 f32
  float* Ksum = KV + NB*NHD*DH*DH;          // 1024 f32
  // total ws use: 96 MB + 132 KB

  dim3 blk(256);
  // q/k/v projections
  gemm_f32in<false><<<dim3(CC/64, MROWS/64), blk, 0, stream>>>(x,   CC, nullptr, Wq, B0, MROWS, CC, CC);
  gemm_f32in<false><<<dim3(CC/64, MROWS/64), blk, 0, stream>>>(src, CC, nullptr, Wk, B1, MROWS, CC, CC);
  gemm_f32in<false><<<dim3(CC/64, MROWS/64), blk, 0, stream>>>(src, CC, nullptr, Wv, B2, MROWS, CC, CC);
  // elu+1 and RoPE on q,k (in place). v/L and *L cancel -> skipped.
  rope_elu_kernel<<<(MROWS*128)/256, blk, 0, stream>>>(B0, B1);
  // KV + Ksum accumulation
  int kvN = NB*NHD*DH*DH + NB*NHD*DH;
  zero_kernel<<<(kvN+255)/256, blk, 0, stream>>>(KV, kvN);
  kv_kernel<<<dim3(NB*NHD, 16), blk, 0, stream>>>(B1, B2, KV, Ksum);
  // attention apply: q(B0) -> attn(B2)
  attn_out_kernel<<<MROWS/16, blk, 0, stream>>>(B0, KV, Ksum, B2);
  // msg = LN1(attn @ Wm^T): attn(B2) -> msg(B0)
  gemm_f32in<false><<<dim3(CC/64, MROWS/64), blk, 0, stream>>>(nullptr, 0, B2, Wm, B0, MROWS, CC, CC);
  ln_kernel<<<MROWS, blk, 0, stream>>>(B0, g1, b1, B0);
  // h1 = relu([x, msg(B0)] @ W1^T) -> B1 (spans B1..B2, 64 MB)
  gemm_f32in<true><<<dim3(2*CC/64, MROWS/64), blk, 0, stream>>>(x, CC, B0, W1, B1, MROWS, 2*CC, 2*CC);
  // h2 = h1(B1) @ W2^T -> B0
  gemm_f32in<false><<<dim3(CC/64, MROWS/64), blk, 0, stream>>>(nullptr, 0, B1, W2, B0, MROWS, CC, 2*CC);
  // out = x + LN2(h2)
  ln_add_kernel<<<MROWS, blk, 0, stream>>>(B0, g2, b2, x, out);
}

// Round 4
// 652.744 us; speedup vs baseline: 2.3251x; 2.3251x over previous
//
#include <hip/hip_runtime.h>
#include <hip/hip_bf16.h>
#include <math.h>

#define NB 4
#define LL 16384
#define CC 256
#define NHD 8
#define DH 32
#define MROWS (NB*LL)   // 65536

typedef __hip_bfloat16 bf16;
typedef __attribute__((ext_vector_type(8))) short short8;
typedef __attribute__((ext_vector_type(4))) float floatx4;

__device__ __forceinline__ float u2f(unsigned short u) {
  return __uint_as_float(((unsigned)u) << 16);
}
__device__ __forceinline__ unsigned short f2u(float f) {
  bf16 t = __float2bfloat16(f);
  unsigned short u;
  __builtin_memcpy(&u, &t, 2);
  return u;
}

// ---------------- MFMA GEMM: C[M,N] = act( A[M,K] @ B[N,K]^T ) -----------
// A row m: k < K0 -> A0 (f32, ld=K0); k >= K0 -> A1 (bf16 ws, ld=K-K0)
// B: f32 weights [N,K]. C: bf16. Tiles 128x128, BK=32, 4 waves of 64x64.
template<bool RELU>
__global__ __launch_bounds__(256) void gemm_mfma(
    const float* __restrict__ A0, int K0, const bf16* __restrict__ A1,
    const float* __restrict__ B, bf16* __restrict__ C,
    int M, int N, int K)
{
  __shared__ __align__(16) unsigned short As[128][40];  // pad 32->40 (80B rows)
  __shared__ __align__(16) unsigned short Bs[128][40];
  const int tid  = threadIdx.x;
  const int lane = tid & 63, wave = tid >> 6;
  const int wm = wave & 1, wn = wave >> 1;
  const int bm = blockIdx.y, bn = blockIdx.x;
  const int l15 = lane & 15, quad = lane >> 4;
  const int sr = tid >> 1, sk = (tid & 1) << 4;   // staging: row, k-offset (16 elems each)

  floatx4 acc[4][4] = {};

  for (int kt = 0; kt < K; kt += 32) {
    // ---- stage A tile (128 x 32 bf16) ----
    {
      int gr = bm*128 + sr;
      int gk = kt + sk;
      unsigned short tmp[16];
      if (gk < K0) {
        const float* p = A0 + (size_t)gr*K0 + gk;
        #pragma unroll
        for (int i = 0; i < 4; i++) {
          float4 f = *(const float4*)(p + i*4);
          tmp[i*4+0]=f2u(f.x); tmp[i*4+1]=f2u(f.y);
          tmp[i*4+2]=f2u(f.z); tmp[i*4+3]=f2u(f.w);
        }
      } else {
        const bf16* p = A1 + (size_t)gr*(size_t)(K-K0) + (gk-K0);
        *(uint4*)(tmp)   = *(const uint4*)(p);
        *(uint4*)(tmp+8) = *(const uint4*)(p+8);
      }
      *(uint4*)&As[sr][sk]   = *(uint4*)(tmp);
      *(uint4*)&As[sr][sk+8] = *(uint4*)(tmp+8);
    }
    // ---- stage B tile (128 x 32 bf16, from f32 weights) ----
    {
      int gc = bn*128 + sr;
      int gk = kt + sk;
      const float* p = B + (size_t)gc*K + gk;
      unsigned short tmp[16];
      #pragma unroll
      for (int i = 0; i < 4; i++) {
        float4 f = *(const float4*)(p + i*4);
        tmp[i*4+0]=f2u(f.x); tmp[i*4+1]=f2u(f.y);
        tmp[i*4+2]=f2u(f.z); tmp[i*4+3]=f2u(f.w);
      }
      *(uint4*)&Bs[sr][sk]   = *(uint4*)(tmp);
      *(uint4*)&Bs[sr][sk+8] = *(uint4*)(tmp+8);
    }
    __syncthreads();
    // ---- fragments + MFMA ----
    short8 a[4], b[4];
    #pragma unroll
    for (int i = 0; i < 4; i++) {
      a[i] = *(const short8*)&As[wm*64 + i*16 + l15][quad*8];
      b[i] = *(const short8*)&Bs[wn*64 + i*16 + l15][quad*8];
    }
    #pragma unroll
    for (int i = 0; i < 4; i++)
      #pragma unroll
      for (int j = 0; j < 4; j++)
        acc[i][j] = __builtin_amdgcn_mfma_f32_16x16x32_bf16(a[i], b[j], acc[i][j], 0, 0, 0);
    __syncthreads();
  }

  // ---- epilogue: C/D layout col=lane&15, row=quad*4+reg ----
  const int row0 = bm*128 + wm*64 + quad*4;
  const int col0 = bn*128 + wn*64 + l15;
  #pragma unroll
  for (int i = 0; i < 4; i++) {
    #pragma unroll
    for (int j = 0; j < 4; j++) {
      #pragma unroll
      for (int r = 0; r < 4; r++) {
        float v = acc[i][j][r];
        if (RELU) v = fmaxf(v, 0.f);
        C[(size_t)(row0 + i*16 + r)*N + (col0 + j*16)] = __float2bfloat16(v);
      }
    }
  }
}

// ---------------- elu+1 then interleaved RoPE, in-place on q and k --------
__global__ __launch_bounds__(256) void rope_elu_kernel(bf16* __restrict__ q, bf16* __restrict__ k)
{
  int idx = blockIdx.x*256 + threadIdx.x;   // one (row, pair); 128 pairs/row
  int row = idx >> 7;
  int p   = idx & 127;          // global pair in row
  int pp  = p & 15;             // pair in head
  int t   = pp >> 1;            // frequency index 0..7
  int l   = row & (LL-1);
  int gi  = l >> 7;             // grid row (W=128)
  int gj  = l & 127;            // grid col
  float pos = (pp & 1) ? (float)(gj+1) : (float)(gi+1);
  float dv  = expf(-1.15129254650564f * (float)t);  // ln(10000)/8
  float ang = pos * dv;
  float s = sinf(ang), c = cosf(ang);
  size_t base = ((size_t)row << 8) + (p << 1);
  ushort2 uq = *(const ushort2*)(q + base);
  float x0 = u2f(uq.x), x1 = u2f(uq.y);
  x0 = x0 > 0.f ? x0 + 1.f : expf(x0);
  x1 = x1 > 0.f ? x1 + 1.f : expf(x1);
  ushort2 oq; oq.x = f2u(fmaf(x0, c, -x1*s)); oq.y = f2u(fmaf(x1, c, x0*s));
  *(ushort2*)(q + base) = oq;
  ushort2 uk = *(const ushort2*)(k + base);
  float y0 = u2f(uk.x), y1 = u2f(uk.y);
  y0 = y0 > 0.f ? y0 + 1.f : expf(y0);
  y1 = y1 > 0.f ? y1 + 1.f : expf(y1);
  ushort2 ok; ok.x = f2u(fmaf(y0, c, -y1*s)); ok.y = f2u(fmaf(y1, c, y0*s));
  *(ushort2*)(k + base) = ok;
}

__global__ __launch_bounds__(256) void zero_kernel(float* __restrict__ p, int n)
{
  int i = blockIdx.x*256 + threadIdx.x;
  if (i < n) p[i] = 0.f;
}

// ---------------- KV[n,h,d,e] = sum_s K[n,s,h,d]*V[n,s,h,e]; Ksum too -----
__global__ __launch_bounds__(256) void kv_kernel(
    const bf16* __restrict__ Kr, const bf16* __restrict__ V,
    float* __restrict__ KV, float* __restrict__ Ksum)
{
  __shared__ __align__(16) float Ks[64][32];
  __shared__ __align__(16) float Vs[64][32];
  const int nh = blockIdx.x;               // n*8+h
  const int n = nh >> 3, h = nh & 7;
  const int s0 = blockIdx.y * 1024;        // 16 chunks of 1024
  const int tid = threadIdx.x;
  const int d = tid >> 3, e0 = (tid & 7) << 2;
  float acc[4] = {0.f,0.f,0.f,0.f};
  float ksl = 0.f;
  for (int sub = 0; sub < 1024; sub += 64) {
    #pragma unroll
    for (int i = 0; i < 4; i++) {
      int flat = (tid + i*256) << 1;        // pair index *2 = element
      int sl = flat >> 5, dd = flat & 31;
      size_t g = (((size_t)(n*LL + s0 + sub + sl) * NHD + h) << 5) + dd;
      ushort2 uk = *(const ushort2*)(Kr + g);
      ushort2 uv = *(const ushort2*)(V + g);
      Ks[sl][dd]   = u2f(uk.x); Ks[sl][dd+1] = u2f(uk.y);
      Vs[sl][dd]   = u2f(uv.x); Vs[sl][dd+1] = u2f(uv.y);
    }
    __syncthreads();
    #pragma unroll 8
    for (int ss = 0; ss < 64; ss++) {
      float kd = Ks[ss][d];
      float4 v4 = *(const float4*)&Vs[ss][e0];
      acc[0] = fmaf(kd, v4.x, acc[0]);
      acc[1] = fmaf(kd, v4.y, acc[1]);
      acc[2] = fmaf(kd, v4.z, acc[2]);
      acc[3] = fmaf(kd, v4.w, acc[3]);
    }
    if (tid < 32) {
      #pragma unroll 8
      for (int ss = 0; ss < 64; ss++) ksl += Ks[ss][tid];
    }
    __syncthreads();
  }
  float* kvp = KV + ((size_t)nh << 10) + (d << 5) + e0;
  atomicAdd(kvp+0, acc[0]); atomicAdd(kvp+1, acc[1]);
  atomicAdd(kvp+2, acc[2]); atomicAdd(kvp+3, acc[3]);
  if (tid < 32) atomicAdd(Ksum + (nh << 5) + tid, ksl);
}

// ---------------- out[l,h,e] = (Q_h . KV_h[:,e]) / (Q_h . Ksum_h + eps) ---
__global__ __launch_bounds__(256) void attn_out_kernel(
    const bf16* __restrict__ Qr, const float* __restrict__ KV,
    const float* __restrict__ Ksum, bf16* __restrict__ Out)
{
  __shared__ float KVs[8192];
  __shared__ float Kss[256];
  __shared__ float Qs[16][256];
  const int blk = blockIdx.x;            // 4096 blocks, 16 rows each
  const int n = blk >> 10;               // 1024 blocks per batch
  const int tid = threadIdx.x;
  const size_t rowBase = (size_t)blk * 16;
  for (int i = tid; i < 8192; i += 256) KVs[i] = KV[((size_t)n << 13) + i];
  Kss[tid] = Ksum[(n << 8) + tid];
  for (int i = tid; i < 4096; i += 256) ((float*)Qs)[i] = u2f(*(const unsigned short*)(Qr + (rowBase << 8) + i));
  __syncthreads();
  const int h = tid >> 5, e = tid & 31;
  const float* kvh = &KVs[(h << 10) + e];
  const float* ksh = &Kss[h << 5];
  for (int r = 0; r < 16; r++) {
    const float* qh = &Qs[r][h << 5];
    float denom = 1e-6f;
    float num = 0.f;
    #pragma unroll
    for (int d = 0; d < 32; d++) {
      float qd = qh[d];
      denom = fmaf(qd, ksh[d], denom);
      num   = fmaf(qd, kvh[d << 5], num);
    }
    Out[((rowBase + r) << 8) + tid] = __float2bfloat16(num / denom);
  }
}

// ---------------- LayerNorm over 256, bf16 ws in/out, f32 params ---------
__global__ __launch_bounds__(256) void ln_kernel(
    const bf16* __restrict__ X, const float* __restrict__ g, const float* __restrict__ b,
    bf16* __restrict__ Out)
{
  __shared__ float ps[4], psq[4], stat[2];
  int row = blockIdx.x, tid = threadIdx.x;
  float v = __bfloat162float(X[((size_t)row << 8) + tid]);
  float s = v, sq = v*v;
  #pragma unroll
  for (int o = 32; o > 0; o >>= 1) {
    s  += __shfl_down(s, o, 64);
    sq += __shfl_down(sq, o, 64);
  }
  if ((tid & 63) == 0) { ps[tid>>6] = s; psq[tid>>6] = sq; }
  __syncthreads();
  if (tid == 0) {
    float S = ps[0]+ps[1]+ps[2]+ps[3];
    float SQ = psq[0]+psq[1]+psq[2]+psq[3];
    float mean = S * (1.f/256.f);
    float var = SQ * (1.f/256.f) - mean*mean;
    stat[0] = mean; stat[1] = rsqrtf(var + 1e-5f);
  }
  __syncthreads();
  float mean = stat[0], rstd = stat[1];
  Out[((size_t)row << 8) + tid] = __float2bfloat16(
      (v - mean)*rstd*g[tid] + b[tid]);
}

// ---------------- final: out = x + LN(h2), f32 in x/out ------------------
__global__ __launch_bounds__(256) void ln_add_kernel(
    const bf16* __restrict__ X, const float* __restrict__ g, const float* __restrict__ b,
    const float* __restrict__ xin, float* __restrict__ Out)
{
  __shared__ float ps[4], psq[4], stat[2];
  int row = blockIdx.x, tid = threadIdx.x;
  size_t idx = ((size_t)row << 8) + tid;
  float v = __bfloat162float(X[idx]);
  float s = v, sq = v*v;
  #pragma unroll
  for (int o = 32; o > 0; o >>= 1) {
    s  += __shfl_down(s, o, 64);
    sq += __shfl_down(sq, o, 64);
  }
  if ((tid & 63) == 0) { ps[tid>>6] = s; psq[tid>>6] = sq; }
  __syncthreads();
  if (tid == 0) {
    float S = ps[0]+ps[1]+ps[2]+ps[3];
    float SQ = psq[0]+psq[1]+psq[2]+psq[3];
    float mean = S * (1.f/256.f);
    float var = SQ * (1.f/256.f) - mean*mean;
    stat[0] = mean; stat[1] = rsqrtf(var + 1e-5f);
  }
  __syncthreads();
  float mean = stat[0], rstd = stat[1];
  float lnv = (v - mean)*rstd*g[tid] + b[tid];
  Out[idx] = xin[idx] + lnv;
}

extern "C" void kernel_launch(void* const* d_in, const int* in_sizes, int n_in,
                              void* d_out, int out_size, void* d_ws, size_t ws_size,
                              hipStream_t stream) {
  const float* x   = (const float*)d_in[0];
  const float* src = (const float*)d_in[1];
  const float* Wq  = (const float*)d_in[2];
  const float* Wk  = (const float*)d_in[3];
  const float* Wv  = (const float*)d_in[4];
  const float* Wm  = (const float*)d_in[5];
  const float* W1  = (const float*)d_in[6];
  const float* W2  = (const float*)d_in[7];
  const float* g1  = (const float*)d_in[8];
  const float* b1  = (const float*)d_in[9];
  const float* g2  = (const float*)d_in[10];
  const float* b2  = (const float*)d_in[11];
  float* out = (float*)d_out;

  bf16* ws = (bf16*)d_ws;
  const size_t BUFH = (size_t)MROWS * CC;   // 16,777,216 bf16 = 32 MB
  bf16* B0 = ws;               // q -> msg -> h2
  bf16* B1 = ws + BUFH;        // k -> h1 (spans B1+B2)
  bf16* B2 = ws + 2*BUFH;      // v -> attn
  float* KV   = (float*)(ws + 3*BUFH);      // 32768 f32
  float* Ksum = KV + NB*NHD*DH*DH;          // 1024 f32
  // total ws use: 96 MB + 132 KB

  dim3 blk(256);
  // q/k/v projections (MFMA)
  gemm_mfma<false><<<dim3(CC/128, MROWS/128), blk, 0, stream>>>(x,   CC, nullptr, Wq, B0, MROWS, CC, CC);
  gemm_mfma<false><<<dim3(CC/128, MROWS/128), blk, 0, stream>>>(src, CC, nullptr, Wk, B1, MROWS, CC, CC);
  gemm_mfma<false><<<dim3(CC/128, MROWS/128), blk, 0, stream>>>(src, CC, nullptr, Wv, B2, MROWS, CC, CC);
  // elu+1 and RoPE on q,k (in place). v/L and *L cancel -> skipped.
  rope_elu_kernel<<<(MROWS*128)/256, blk, 0, stream>>>(B0, B1);
  // KV + Ksum accumulation
  int kvN = NB*NHD*DH*DH + NB*NHD*DH;
  zero_kernel<<<(kvN+255)/256, blk, 0, stream>>>(KV, kvN);
  kv_kernel<<<dim3(NB*NHD, 16), blk, 0, stream>>>(B1, B2, KV, Ksum);
  // attention apply: q(B0) -> attn(B2)
  attn_out_kernel<<<MROWS/16, blk, 0, stream>>>(B0, KV, Ksum, B2);
  // msg = LN1(attn @ Wm^T): attn(B2) -> msg(B0)
  gemm_mfma<false><<<dim3(CC/128, MROWS/128), blk, 0, stream>>>(nullptr, 0, B2, Wm, B0, MROWS, CC, CC);
  ln_kernel<<<MROWS, blk, 0, stream>>>(B0, g1, b1, B0);
  // h1 = relu([x, msg(B0)] @ W1^T) -> B1 (spans B1..B2, 64 MB)
  gemm_mfma<true><<<dim3(2*CC/128, MROWS/128), blk, 0, stream>>>(x, CC, B0, W1, B1, MROWS, 2*CC, 2*CC);
  // h2 = h1(B1) @ W2^T -> B0
  gemm_mfma<false><<<dim3(CC/128, MROWS/128), blk, 0, stream>>>(nullptr, 0, B1, W2, B0, MROWS, CC, 2*CC);
  // out = x + LN2(h2)
  ln_add_kernel<<<MROWS, blk, 0, stream>>>(B0, g2, b2, x, out);
}